// Round 4
// baseline (296.049 us; speedup 1.0000x reference)
//
#include <hip/hip_runtime.h>
#include <hip/hip_bf16.h>

typedef __attribute__((ext_vector_type(8))) short bf16x8;
typedef __attribute__((ext_vector_type(4))) float f32x4;

#define B_SZ   1024
#define T_SZ   128
#define L_SZ   256
#define F_SZ   784
#define M_TOT  (B_SZ * T_SZ)            // 131072
#define BK     32
#define KSTEPS 25                       // ceil(784/32), tail zero-padded

#define WPRE_ELEMS (KSTEPS * 4 * L_SZ)  // 25600 bf16x8 elements
#define WPRE_BYTES (WPRE_ELEMS * 16)    // 409600
#define CDIFF_ELEMS (T_SZ * L_SZ)       // 32768
#define WS_NEED (WPRE_BYTES + CDIFF_ELEMS * 4)

__device__ __forceinline__ unsigned short f2bf(float f) {
    __hip_bfloat16 h = __float2bfloat16(f);   // RTNE
    return *reinterpret_cast<unsigned short*>(&h);
}

// ---------------- prep: W -> bf16 MFMA-fragment layout; cdiff = c0 - c1 ----
// wpre[ks][kgrp][leaf] : bf16x8 = W[leaf][ks*32+kgrp*8 .. +8), 0-padded tail
__global__ __launch_bounds__(256) void dn_prep(
    const float* __restrict__ W, const float* __restrict__ contrib,
    unsigned short* __restrict__ wpre, float* __restrict__ cdiff)
{
    const int gid = blockIdx.x * 256 + threadIdx.x;
    if (gid < WPRE_ELEMS) {
        const int leaf = gid & 255;
        const int kg   = (gid >> 8) & 3;
        const int ks   = gid >> 10;
        const int k0   = ks * BK + kg * 8;
        bf16x8 v;
        #pragma unroll
        for (int j = 0; j < 8; ++j) {
            const int k = k0 + j;
            const float f = (k < F_SZ) ? W[(size_t)leaf * F_SZ + k] : 0.f;
            v[j] = (short)f2bf(f);
        }
        *reinterpret_cast<bf16x8*>(wpre + (size_t)gid * 8) = v;
    } else {
        const int cid = gid - WPRE_ELEMS;
        if (cid < CDIFF_ELEMS)
            cdiff[cid] = contrib[(size_t)cid * 2] - contrib[(size_t)cid * 2 + 1];
    }
}

// ---------------- v3b: no LDS, no barriers — pure streaming MFMA -----------
// Each wave: 32 rows x 128 cols. Block = 4 waves = 128 rows x 128 cols.
// Grid 2048: bid -> rowGroup=(bid>>4<<3)|(bid&7), colHalf=(bid>>3)&1 so the
// two col-halves of the same rows land on the SAME XCD (bid%8 preserved),
// 8 dispatches apart -> x L2/L3 reuse, HBM reads x ~once.
__global__ __launch_bounds__(256, 2) void dn_fused3(
    const float* __restrict__ x, const unsigned short* __restrict__ wpre,
    const float* __restrict__ bias, const float* __restrict__ cdiff,
    float* __restrict__ out)
{
    const int tid  = threadIdx.x;
    const int lane = tid & 63;
    const int wid  = tid >> 6;          // 0..3
    const int lr   = lane & 15;
    const int kseg = lane >> 4;         // 0..3 (k sub-slice of 8)

    const int bid      = blockIdx.x;
    const int rowGroup = ((bid >> 4) << 3) | (bid & 7);   // 0..1023
    const int colHalf  = (bid >> 3) & 1;
    const int rowBase  = rowGroup * 128 + wid * 32;       // wave's first row
    const int colBase  = colHalf * 128;                   // wave's first col

    // per-lane base pointers (K-step offsets fold to immediates after unroll)
    const float* xp0 = x + (size_t)(rowBase + lr) * F_SZ + kseg * 8;       // mi=0
    const float* xp1 = xp0 + (size_t)16 * F_SZ;                            // mi=1
    const unsigned short* wp = wpre + ((size_t)kseg * L_SZ + colBase + lr) * 8;

    f32x4 acc[2][8];
    #pragma unroll
    for (int mi = 0; mi < 2; ++mi)
        #pragma unroll
        for (int ni = 0; ni < 8; ++ni)
            acc[mi][ni] = (f32x4){0.f, 0.f, 0.f, 0.f};

    #pragma unroll
    for (int ks = 0; ks < 24; ++ks) {   // full steps: k in [0,768), always in-bounds
        const f32x4 a00 = *reinterpret_cast<const f32x4*>(xp0 + ks * 32);
        const f32x4 a01 = *reinterpret_cast<const f32x4*>(xp0 + ks * 32 + 4);
        const f32x4 a10 = *reinterpret_cast<const f32x4*>(xp1 + ks * 32);
        const f32x4 a11 = *reinterpret_cast<const f32x4*>(xp1 + ks * 32 + 4);

        bf16x8 bv[8];
        #pragma unroll
        for (int ni = 0; ni < 8; ++ni)
            bv[ni] = *reinterpret_cast<const bf16x8*>(wp + (size_t)ks * 8192 + ni * 128);

        bf16x8 a0, a1;
        #pragma unroll
        for (int j = 0; j < 4; ++j) {
            a0[j]     = (short)f2bf(a00[j]);
            a0[4 + j] = (short)f2bf(a01[j]);
            a1[j]     = (short)f2bf(a10[j]);
            a1[4 + j] = (short)f2bf(a11[j]);
        }

        #pragma unroll
        for (int ni = 0; ni < 8; ++ni) {
            acc[0][ni] = __builtin_amdgcn_mfma_f32_16x16x32_bf16(a0, bv[ni], acc[0][ni], 0, 0, 0);
            acc[1][ni] = __builtin_amdgcn_mfma_f32_16x16x32_bf16(a1, bv[ni], acc[1][ni], 0, 0, 0);
        }
    }

    {   // tail step ks=24: k = 768 + kseg*8. Valid only for kseg<2 (768..783).
        // wpre is zero-padded for k>=784, so A values for kseg>=2 are
        // multiplied by 0 — only the ADDRESS must stay in-bounds: clamp to
        // row offset 0 (one cndmask on the address, values irrelevant).
        const int toff = (kseg < 2) ? 768 : -(kseg * 8);
        const f32x4 a00 = *reinterpret_cast<const f32x4*>(xp0 + toff);
        const f32x4 a01 = *reinterpret_cast<const f32x4*>(xp0 + toff + 4);
        const f32x4 a10 = *reinterpret_cast<const f32x4*>(xp1 + toff);
        const f32x4 a11 = *reinterpret_cast<const f32x4*>(xp1 + toff + 4);

        bf16x8 bv[8];
        #pragma unroll
        for (int ni = 0; ni < 8; ++ni)
            bv[ni] = *reinterpret_cast<const bf16x8*>(wp + (size_t)24 * 8192 + ni * 128);

        bf16x8 a0, a1;
        #pragma unroll
        for (int j = 0; j < 4; ++j) {
            a0[j]     = (short)f2bf(a00[j]);
            a0[4 + j] = (short)f2bf(a01[j]);
            a1[j]     = (short)f2bf(a10[j]);
            a1[4 + j] = (short)f2bf(a11[j]);
        }

        #pragma unroll
        for (int ni = 0; ni < 8; ++ni) {
            acc[0][ni] = __builtin_amdgcn_mfma_f32_16x16x32_bf16(a0, bv[ni], acc[0][ni], 0, 0, 0);
            acc[1][ni] = __builtin_amdgcn_mfma_f32_16x16x32_bf16(a1, bv[ni], acc[1][ni], 0, 0, 0);
        }
    }

    // epilogue: sp = clip(acc + b); gini = 1 + 2 s (1-s), s = sigmoid(sp*cdiff)
    const size_t GOFF = (size_t)M_TOT * L_SZ;
    #pragma unroll
    for (int ni = 0; ni < 8; ++ni) {
        const int col = colBase + ni * 16 + lr;
        const float bb = bias[col];
        #pragma unroll
        for (int mi = 0; mi < 2; ++mi) {
            #pragma unroll
            for (int r = 0; r < 4; ++r) {
                const int m = rowBase + mi * 16 + kseg * 4 + r;   // C/D row map
                const int t = m & (T_SZ - 1);
                float v  = acc[mi][ni][r] + bb;
                float sp = fminf(fmaxf(v, -1.f), 1.f);
                const float d  = sp * cdiff[t * L_SZ + col];
                const float ed = __expf(d);
                const float s  = ed / (1.f + ed);
                const float g  = fmaf(2.f * s, 1.f - s, 1.f);
                const size_t o = (size_t)m * L_SZ + col;
                out[o]        = sp;
                out[GOFF + o] = g;
            }
        }
    }
}

// ---------------- v1 fallback (no workspace needed) ------------------------
__global__ __launch_bounds__(512) void dn_fused_v1(
    const float* __restrict__ x, const float* __restrict__ W,
    const float* __restrict__ bias, const float* __restrict__ contrib,
    float* __restrict__ out)
{
    __shared__ bf16x8 As[4][128];
    __shared__ bf16x8 Bs[4][L_SZ];

    const int tid    = threadIdx.x;
    const int lane   = tid & 63;
    const int wid    = tid >> 6;
    const int waveM  = wid >> 2;
    const int waveN  = wid & 3;
    const int blkRow = blockIdx.x * 128;
    const int ar = tid >> 2;
    const int ak = (tid & 3) * 8;
    const int wr = tid >> 1;
    const int wk = (tid & 1) * 16;
    const int laneRow = lane & 15;
    const int kgrp    = lane >> 4;

    f32x4 acc[4][4];
    #pragma unroll
    for (int i = 0; i < 4; ++i)
        #pragma unroll
        for (int j = 0; j < 4; ++j)
            acc[i][j] = (f32x4){0.f, 0.f, 0.f, 0.f};

    const float* xrow = x + (size_t)(blkRow + ar) * F_SZ;
    const float* wrow = W + (size_t)wr * F_SZ;
    const f32x4 zf = {0.f, 0.f, 0.f, 0.f};

    f32x4 xa0 = *reinterpret_cast<const f32x4*>(xrow + ak);
    f32x4 xa1 = *reinterpret_cast<const f32x4*>(xrow + ak + 4);
    f32x4 wa0 = *reinterpret_cast<const f32x4*>(wrow + wk);
    f32x4 wa1 = *reinterpret_cast<const f32x4*>(wrow + wk + 4);
    f32x4 wa2 = *reinterpret_cast<const f32x4*>(wrow + wk + 8);
    f32x4 wa3 = *reinterpret_cast<const f32x4*>(wrow + wk + 12);

    for (int ks = 0; ks < KSTEPS; ++ks) {
        bf16x8 av, wv0, wv1;
        #pragma unroll
        for (int j = 0; j < 4; ++j) {
            av[j]      = (short)f2bf(xa0[j]);
            av[4 + j]  = (short)f2bf(xa1[j]);
            wv0[j]     = (short)f2bf(wa0[j]);
            wv0[4 + j] = (short)f2bf(wa1[j]);
            wv1[j]     = (short)f2bf(wa2[j]);
            wv1[4 + j] = (short)f2bf(wa3[j]);
        }
        As[ak >> 3][ar] = av;
        Bs[wk >> 3][wr] = wv0;
        Bs[(wk >> 3) + 1][wr] = wv1;
        __syncthreads();

        if (ks + 1 < KSTEPS) {
            const int kb = (ks + 1) * BK;
            if (kb + ak < F_SZ) {
                xa0 = *reinterpret_cast<const f32x4*>(xrow + kb + ak);
                xa1 = *reinterpret_cast<const f32x4*>(xrow + kb + ak + 4);
            } else { xa0 = zf; xa1 = zf; }
            if (kb + wk < F_SZ) {
                wa0 = *reinterpret_cast<const f32x4*>(wrow + kb + wk);
                wa1 = *reinterpret_cast<const f32x4*>(wrow + kb + wk + 4);
                wa2 = *reinterpret_cast<const f32x4*>(wrow + kb + wk + 8);
                wa3 = *reinterpret_cast<const f32x4*>(wrow + kb + wk + 12);
            } else { wa0 = zf; wa1 = zf; wa2 = zf; wa3 = zf; }
        }

        bf16x8 af[4], bfv[4];
        #pragma unroll
        for (int mi = 0; mi < 4; ++mi)
            af[mi] = As[kgrp][waveM * 64 + mi * 16 + laneRow];
        #pragma unroll
        for (int ni = 0; ni < 4; ++ni)
            bfv[ni] = Bs[kgrp][waveN * 64 + ni * 16 + laneRow];
        #pragma unroll
        for (int mi = 0; mi < 4; ++mi)
            #pragma unroll
            for (int ni = 0; ni < 4; ++ni)
                acc[mi][ni] = __builtin_amdgcn_mfma_f32_16x16x32_bf16(
                    af[mi], bfv[ni], acc[mi][ni], 0, 0, 0);
        __syncthreads();
    }

    const size_t GOFF  = (size_t)M_TOT * L_SZ;
    const int    rbase = waveM * 64 + (lane >> 4) * 4;
    const int    cbase = waveN * 64 + laneRow;
    #pragma unroll
    for (int ni = 0; ni < 4; ++ni) {
        const int col = cbase + ni * 16;
        const float bb = bias[col];
        #pragma unroll
        for (int mi = 0; mi < 4; ++mi) {
            #pragma unroll
            for (int r = 0; r < 4; ++r) {
                const int m = blkRow + rbase + mi * 16 + r;
                const int t = m & (T_SZ - 1);
                float v  = acc[mi][ni][r] + bb;
                float sp = fminf(fmaxf(v, -1.f), 1.f);
                const float* cp = contrib + (size_t)(t * L_SZ + col) * 2;
                const float d  = sp * (cp[0] - cp[1]);
                const float ed = __expf(d);
                const float s  = ed / (1.f + ed);
                const float g  = fmaf(2.f * s, 1.f - s, 1.f);
                const size_t o = (size_t)m * L_SZ + col;
                out[o]        = sp;
                out[GOFF + o] = g;
            }
        }
    }
}

extern "C" void kernel_launch(void* const* d_in, const int* in_sizes, int n_in,
                              void* d_out, int out_size, void* d_ws, size_t ws_size,
                              hipStream_t stream) {
    const float* x       = (const float*)d_in[0];
    const float* W       = (const float*)d_in[1];
    const float* bias    = (const float*)d_in[2];
    const float* contrib = (const float*)d_in[3];
    float* out = (float*)d_out;

    if (ws_size >= (size_t)WS_NEED && d_ws != nullptr) {
        unsigned short* wpre  = (unsigned short*)d_ws;
        float*          cdiff = (float*)((char*)d_ws + WPRE_BYTES);
        const int prep_threads = WPRE_ELEMS + CDIFF_ELEMS;
        dn_prep<<<(prep_threads + 255) / 256, 256, 0, stream>>>(W, contrib, wpre, cdiff);
        dn_fused3<<<2048, 256, 0, stream>>>(x, wpre, bias, cdiff, out);
    } else {
        dn_fused_v1<<<M_TOT / 128, 512, 0, stream>>>(x, W, bias, contrib, out);
    }
}